// Round 1
// baseline (430.329 us; speedup 1.0000x reference)
//
#include <hip/hip_runtime.h>
#include <stdint.h>

// Problem dims (fixed by reference)
#define M_ROWS 8192
#define K_DIM  4096
#define NCOLS  128     // fused layer-1 cols: [0,64)=C branch, [64,128)=R branch
#define OUTD   144     // per-branch flat size (78 real + 66 imag)
#define PLANE  1179648 // complex elements per output (8192*144)

typedef __attribute__((ext_vector_type(4))) float  float4v;
typedef __attribute__((ext_vector_type(8))) short  short8v;
typedef __attribute__((ext_vector_type(4))) short  short4v;

static __device__ __forceinline__ unsigned short f2bf(float f) {
    // round-to-nearest-even fp32 -> bf16
    unsigned int u = __builtin_bit_cast(unsigned int, f);
    u += 0x7FFFu + ((u >> 16) & 1u);
    return (unsigned short)(u >> 16);
}

// ---------------------------------------------------------------------------
// Prep: Wt[n][k] = W1[k][n] as bf16, n in [0,128) = [WC1 cols | WR1 cols]
// ---------------------------------------------------------------------------
__global__ __launch_bounds__(256) void wt_kernel(
    const float* __restrict__ WC1, const float* __restrict__ WR1,
    unsigned short* __restrict__ Wt) {
    __shared__ float tile[64][65];
    const float* src = (blockIdx.y == 0) ? WC1 : WR1;
    const int k0 = blockIdx.x * 64;
    const int t = threadIdx.x;
    const int j = t & 63, q = t >> 6;
#pragma unroll
    for (int p = 0; p < 16; ++p) {
        int i = p * 4 + q;
        tile[i][j] = src[(size_t)(k0 + i) * 64 + j];
    }
    __syncthreads();
#pragma unroll
    for (int p = 0; p < 16; ++p) {
        int n = p * 4 + q;
        Wt[(size_t)(blockIdx.y * 64 + n) * K_DIM + k0 + j] = f2bf(tile[j][n]);
    }
}

// ---------------------------------------------------------------------------
// Fused: per 16-row tile, GEMM1 (bf16 MFMA, BK=128, reg-prefetch ping-pong)
// -> layer2 -> layer3 -> Cholesky outer product, one aliased LDS region.
// 512 threads (8 waves; wave w owns output cols [16w,16w+16)).
// Output bf16, IM-FIRST INTERLEAVED: flat[2q]=Im, flat[2q+1]=Re,
// q = b*144 + i*12 + j; C block at [0,2*PLANE), R at [2*PLANE,4*PLANE).
// ---------------------------------------------------------------------------
__global__ __launch_bounds__(512, 4) void fused_kernel(
    const float* __restrict__ X, const unsigned short* __restrict__ Wt,
    const float* __restrict__ bC1, const float* __restrict__ bR1,
    const float* __restrict__ WC2, const float* __restrict__ bC2,
    const float* __restrict__ WR2, const float* __restrict__ bR2,
    const float* __restrict__ WC3, const float* __restrict__ bC3,
    const float* __restrict__ WR3, const float* __restrict__ bR3,
    unsigned short* __restrict__ OUT) {
    // LDS union (41216 B -> 2 blocks/CU):
    //  phase1: Asm [16][136] u16 (4352 B) | Bsm [128][136] u16 (34816 B)
    //  phase2: hs  [16][132] f32 (8448 B) | W2s [64][128] f32 (32768 B)
    //  phase3+: fl [16][288] f32 (18432 B) overlays W2s
    __shared__ __align__(16) char smem[41216];
    unsigned short* Asm_ = (unsigned short*)smem;          // [16][136]
    unsigned short* Bsm_ = Asm_ + 16 * 136;                // [128][136]
    float* hs  = (float*)smem;                             // [16][132]
    float* W2s = hs + 16 * 132;                            // [64][128]
    float* fl  = W2s;                                      // [16][288]

    const int tid  = threadIdx.x;       // 0..511
    const int lane = tid & 63;
    const int w    = tid >> 6;          // wave 0..7 -> col tile [16w, 16w+16)
    const int r0   = blockIdx.x * 16;
    const int m    = lane & 15, q = lane >> 4;
    const int ar   = tid >> 5, akc = tid & 31;  // A staging: row, k-quad

    float4v acc = {0.f, 0.f, 0.f, 0.f};

    // ---------------- Phase 1: GEMM1 (16 x 4096 @ 4096 x 128, bf16 MFMA) ----
    // BK=128 per step; ping-pong register prefetch one tile ahead.
    const float* xp = X + (size_t)(r0 + ar) * K_DIM + akc * 4;
    const unsigned short* wp = Wt + (size_t)(tid >> 4) * K_DIM + (tid & 15) * 8;
    unsigned short* aw = &Asm_[ar * 136 + akc * 4];
    unsigned short* bw = &Bsm_[(tid >> 4) * 136 + (tid & 15) * 8];

    float4 xa, xb; uint4 ba[4], bb[4];

    auto LOADT = [&](int kk, float4& x, uint4* b) {
        x = *(const float4*)(xp + kk);
#pragma unroll
        for (int p = 0; p < 4; ++p)
            b[p] = *(const uint4*)(wp + (size_t)p * 32 * K_DIM + kk);
    };
    auto STORET = [&](const float4& x, const uint4* b) {
        short4v s;
        s.x = (short)f2bf(x.x); s.y = (short)f2bf(x.y);
        s.z = (short)f2bf(x.z); s.w = (short)f2bf(x.w);
        *(short4v*)aw = s;
#pragma unroll
        for (int p = 0; p < 4; ++p)
            *(uint4*)(bw + p * 32 * 136) = b[p];
    };
    auto MF = [&]() {
#pragma unroll
        for (int ks = 0; ks < 4; ++ks) {
            short8v a = *(const short8v*)&Asm_[m * 136 + ks * 32 + q * 8];
            short8v b = *(const short8v*)&Bsm_[(w * 16 + m) * 136 + ks * 32 + q * 8];
            acc = __builtin_amdgcn_mfma_f32_16x16x32_bf16(a, b, acc, 0, 0, 0);
        }
    };

    LOADT(0, xa, ba);
#pragma unroll 1
    for (int kk = 0; kk < K_DIM; kk += 256) {
        STORET(xa, ba);
        __syncthreads();
        LOADT(kk + 128, xb, bb);       // prefetch: covered by MFMA + barrier
        MF();
        __syncthreads();
        STORET(xb, bb);
        __syncthreads();
        if (kk + 256 < K_DIM) LOADT(kk + 256, xa, ba);
        MF();
        __syncthreads();
    }

    // Epilogue: C/D layout col=lane&15, row=quad*4+reg. Write h1 into hs.
    {
        const int c = w * 16 + m;
        const float bv = (c < 64) ? bC1[c] : bR1[c - 64];
#pragma unroll
        for (int i = 0; i < 4; ++i) {
            int r = q * 4 + i;
            float v = acc[i] + bv; v = v > 0.f ? v : 0.f;
            hs[r * 132 + c] = v;
        }
    }
    // Stage W2 = [WC2 | WR2] into LDS (64 x 128 f32), 2048 float4 / 512 thr.
#pragma unroll
    for (int p = 0; p < 4; ++p) {
        int fi = p * 512 + tid;
        int k = fi >> 5, c4 = fi & 31;
        int c = c4 * 4;
        const float* wsrc = (c < 64) ? (WC2 + (size_t)k * 64 + c)
                                     : (WR2 + (size_t)k * 64 + (c - 64));
        *(float4*)&W2s[k * 128 + c] = *(const float4*)wsrc;
    }
    __syncthreads();

    // ---------------- Phase 2: layer 2 (h2 = relu(h1 @ W2 + b2)) -----------
    const int rg = tid >> 5;          // 16 rows, 1 per row-group
    const int cg = tid & 31;          // 32 col quads
    const int koff2 = (cg < 16) ? 0 : 64;
    float acc2[4];
    {
        int c = cg * 4;
        const float* bsrc = (c < 64) ? (bC2 + c) : (bR2 + (c - 64));
#pragma unroll
        for (int j = 0; j < 4; ++j) acc2[j] = bsrc[j];
    }
    for (int k = 0; k < 64; ++k) {
        float4 wv = *(const float4*)&W2s[k * 128 + cg * 4];
        float a = hs[rg * 132 + koff2 + k];
        acc2[0] += a * wv.x; acc2[1] += a * wv.y;
        acc2[2] += a * wv.z; acc2[3] += a * wv.w;
    }
    float4 h2v;
    h2v.x = acc2[0] > 0.f ? acc2[0] : 0.f;
    h2v.y = acc2[1] > 0.f ? acc2[1] : 0.f;
    h2v.z = acc2[2] > 0.f ? acc2[2] : 0.f;
    h2v.w = acc2[3] > 0.f ? acc2[3] : 0.f;
    __syncthreads();                   // all reads of hs(h1)/W2s done
    *(float4*)&hs[rg * 132 + cg * 4] = h2v;   // hs now holds h2
    __syncthreads();

    // ---------------- Phase 3: layer 3 -> fl[16][288] (overlays W2s) -------
#pragma unroll 1
    for (int pass = 0; pass < 3; ++pass) {
        int c = pass * 128 + cg * 4;
        if (c < 288) {
            const int brn = (c >= 144);
            const int cl = c - (brn ? 144 : 0);
            const float* W3 = brn ? WR3 : WC3;
            const float* b3 = brn ? bR3 : bC3;
            const int ko = brn ? 64 : 0;
            float a3[4];
#pragma unroll
            for (int j = 0; j < 4; ++j) a3[j] = b3[cl + j];
            for (int k = 0; k < 64; ++k) {
                float4 wv = *(const float4*)(W3 + (size_t)k * OUTD + cl);
                float a = hs[rg * 132 + ko + k];
                a3[0] += a * wv.x; a3[1] += a * wv.y;
                a3[2] += a * wv.z; a3[3] += a * wv.w;
            }
            float4 v; v.x = a3[0]; v.y = a3[1]; v.z = a3[2]; v.w = a3[3];
            *(float4*)&fl[rg * 288 + c] = v;
        }
    }
    __syncthreads();

    // ---------------- Phase 4: softplus on the 12 diag reals per (row,brn) -
    if (tid < 384) {
        int r = tid / 24, rem = tid % 24;
        int brn = rem / 12, ii = rem % 12;
        float* f = &fl[r * 288 + brn * 144];
        int d = ii * (ii + 1) / 2 + ii;
        float xv = f[d];
        f[d] = (xv > 20.f) ? xv : log1pf(expf(xv));
    }
    __syncthreads();

    // ---------------- Phase 5: C = L L^H, Hermitian mirror, write OUT ------
    // IM-FIRST interleaved: one u32 = (re<<16)|im per complex element.
    unsigned int* O32 = (unsigned int*)OUT;
    for (int task = tid; task < 16 * 2 * 78; task += 512) {
        int r = task / 156, rem = task % 156;
        int brn = rem / 78, p = rem % 78;
        int i = 0;
        while (p >= (i + 1) * (i + 2) / 2) ++i;
        int j = p - i * (i + 1) / 2;              // j <= i
        const float* f = &fl[r * 288 + brn * 144]; // reals (diag softplus'd)
        const float* g = f + 78;                   // strict-lower imags
        const int ti = i * (i + 1) / 2, tj = j * (j + 1) / 2;
        const int si = i * (i - 1) / 2, sj = j * (j - 1) / 2;
        float re = 0.f, im = 0.f;
        for (int k = 0; k <= j; ++k) {
            float ar_ = f[ti + k];
            float ai  = (k == i) ? 0.f : g[si + k];
            float br_ = f[tj + k];
            float bi  = (k == j) ? 0.f : g[sj + k];
            re += ar_ * br_ + ai * bi;             // Re(L[i] . conj(L[j]))
            im += ai * br_ - ar_ * bi;             // Im
        }
        unsigned int reb = (unsigned int)f2bf(re);
        unsigned int imb = (unsigned int)f2bf(im);
        unsigned int imn = (unsigned int)f2bf(-im);
        size_t base = brn ? (size_t)PLANE : 0;     // in u32 units
        size_t q1 = (size_t)(r0 + r) * 144 + (size_t)(i * 12 + j);
        O32[base + q1] = imb | (reb << 16);        // imag low, real high
        if (i != j) {
            size_t q2 = (size_t)(r0 + r) * 144 + (size_t)(j * 12 + i);
            O32[base + q2] = imn | (reb << 16);
        }
    }
}

// ---------------------------------------------------------------------------
extern "C" void kernel_launch(void* const* d_in, const int* in_sizes, int n_in,
                              void* d_out, int out_size, void* d_ws, size_t ws_size,
                              hipStream_t stream) {
    const float* X   = (const float*)d_in[0];
    const float* WC1 = (const float*)d_in[1];
    const float* bC1 = (const float*)d_in[2];
    const float* WC2 = (const float*)d_in[3];
    const float* bC2 = (const float*)d_in[4];
    const float* WC3 = (const float*)d_in[5];
    const float* bC3 = (const float*)d_in[6];
    const float* WR1 = (const float*)d_in[7];
    const float* bR1 = (const float*)d_in[8];
    const float* WR2 = (const float*)d_in[9];
    const float* bR2 = (const float*)d_in[10];
    const float* WR3 = (const float*)d_in[11];
    const float* bR3 = (const float*)d_in[12];

    unsigned short* Wt = (unsigned short*)d_ws;   // 128 x 4096 bf16 = 1 MB
    unsigned short* OUT = (unsigned short*)d_out; // bf16, im-first interleaved

    wt_kernel<<<dim3(64, 2), 256, 0, stream>>>(WC1, WR1, Wt);
    fused_kernel<<<M_ROWS / 16, 512, 0, stream>>>(
        X, Wt, bC1, bR1, WC2, bC2, WR2, bR2, WC3, bC3, WR3, bR3, OUT);
}

// Round 5
// 259.169 us; speedup vs baseline: 1.6604x; 1.6604x over previous
//
#include <hip/hip_runtime.h>
#include <stdint.h>

// Problem dims (fixed by reference)
#define M_ROWS 8192
#define K_DIM  4096
#define NCOLS  128     // fused layer-1 cols: [0,64)=C branch, [64,128)=R branch
#define OUTD   144     // per-branch flat size (78 real + 66 imag)
#define PLANE  1179648 // complex elements per output (8192*144)

typedef __attribute__((ext_vector_type(4))) float  float4v;
typedef __attribute__((ext_vector_type(8))) short  short8v;
typedef __attribute__((ext_vector_type(4))) short  short4v;

static __device__ __forceinline__ unsigned short f2bf(float f) {
    // round-to-nearest-even fp32 -> bf16
    unsigned int u = __builtin_bit_cast(unsigned int, f);
    u += 0x7FFFu + ((u >> 16) & 1u);
    return (unsigned short)(u >> 16);
}

// ---------------------------------------------------------------------------
// Prep: Wt[n][k] = W1[k][n] as bf16, n in [0,128) = [WC1 cols | WR1 cols]
// ---------------------------------------------------------------------------
__global__ __launch_bounds__(256) void wt_kernel(
    const float* __restrict__ WC1, const float* __restrict__ WR1,
    unsigned short* __restrict__ Wt) {
    __shared__ float tile[64][65];
    const float* src = (blockIdx.y == 0) ? WC1 : WR1;
    const int k0 = blockIdx.x * 64;
    const int t = threadIdx.x;
    const int j = t & 63, q = t >> 6;
#pragma unroll
    for (int p = 0; p < 16; ++p) {
        int i = p * 4 + q;
        tile[i][j] = src[(size_t)(k0 + i) * 64 + j];
    }
    __syncthreads();
#pragma unroll
    for (int p = 0; p < 16; ++p) {
        int n = p * 4 + q;
        Wt[(size_t)(blockIdx.y * 64 + n) * K_DIM + k0 + j] = f2bf(tile[j][n]);
    }
}

// ---------------------------------------------------------------------------
// Fused: per 16-row tile, GEMM1 (bf16 MFMA, BK=128, reg-prefetch ping-pong
// with NAMED registers — no address-taken arrays, no scratch) -> layer2 ->
// layer3 -> Cholesky outer product, one aliased LDS region.
// 512 threads (8 waves; wave w owns output cols [16w,16w+16)).
// Output bf16, IM-FIRST INTERLEAVED: flat[2q]=Im, flat[2q+1]=Re,
// q = b*144 + i*12 + j; C block at [0,2*PLANE), R at [2*PLANE,4*PLANE).
// ---------------------------------------------------------------------------
// NOTE: macro params use trailing-underscore names so they can never collide
// with vector member tokens (.x/.y/.z/.w) during substitution.

#define LOADT(KK_, X_, B0_, B1_, B2_, B3_)                              \
    do {                                                                \
        X_  = *(const float4*)(xp + (KK_));                             \
        B0_ = *(const uint4*)(wp + (size_t)(0 * 32) * K_DIM + (KK_));   \
        B1_ = *(const uint4*)(wp + (size_t)(1 * 32) * K_DIM + (KK_));   \
        B2_ = *(const uint4*)(wp + (size_t)(2 * 32) * K_DIM + (KK_));   \
        B3_ = *(const uint4*)(wp + (size_t)(3 * 32) * K_DIM + (KK_));   \
    } while (0)

#define STORET(X_, B0_, B1_, B2_, B3_)                                  \
    do {                                                                \
        short4v s_;                                                     \
        s_.x = (short)f2bf((X_).x); s_.y = (short)f2bf((X_).y);         \
        s_.z = (short)f2bf((X_).z); s_.w = (short)f2bf((X_).w);         \
        *(short4v*)aw = s_;                                             \
        *(uint4*)(bw + 0 * 32 * 136) = B0_;                             \
        *(uint4*)(bw + 1 * 32 * 136) = B1_;                             \
        *(uint4*)(bw + 2 * 32 * 136) = B2_;                             \
        *(uint4*)(bw + 3 * 32 * 136) = B3_;                             \
    } while (0)

#define MF()                                                                     \
    do {                                                                         \
        _Pragma("unroll")                                                        \
        for (int ks = 0; ks < 4; ++ks) {                                         \
            short8v a_ = *(const short8v*)&Asm_[m * 136 + ks * 32 + q * 8];      \
            short8v b_ = *(const short8v*)&Bsm_[(w * 16 + m) * 136 + ks * 32 + q * 8]; \
            acc = __builtin_amdgcn_mfma_f32_16x16x32_bf16(a_, b_, acc, 0, 0, 0); \
        }                                                                        \
    } while (0)

__global__ __launch_bounds__(512, 4) void fused_kernel(
    const float* __restrict__ X, const unsigned short* __restrict__ Wt,
    const float* __restrict__ bC1, const float* __restrict__ bR1,
    const float* __restrict__ WC2, const float* __restrict__ bC2,
    const float* __restrict__ WR2, const float* __restrict__ bR2,
    const float* __restrict__ WC3, const float* __restrict__ bC3,
    const float* __restrict__ WR3, const float* __restrict__ bR3,
    unsigned short* __restrict__ OUT) {
    // LDS union (41216 B -> 2 blocks/CU):
    //  phase1: Asm [16][136] u16 (4352 B) | Bsm [128][136] u16 (34816 B)
    //  phase2: hs  [16][132] f32 (8448 B) | W2s [64][128] f32 (32768 B)
    //  phase3+: fl [16][288] f32 (18432 B) overlays W2s
    __shared__ __align__(16) char smem[41216];
    unsigned short* Asm_ = (unsigned short*)smem;          // [16][136]
    unsigned short* Bsm_ = Asm_ + 16 * 136;                // [128][136]
    float* hs  = (float*)smem;                             // [16][132]
    float* W2s = hs + 16 * 132;                            // [64][128]
    float* fl  = W2s;                                      // [16][288]

    const int tid  = threadIdx.x;       // 0..511
    const int lane = tid & 63;
    const int w    = tid >> 6;          // wave 0..7 -> col tile [16w, 16w+16)
    const int r0   = blockIdx.x * 16;
    const int m    = lane & 15, q = lane >> 4;
    const int ar   = tid >> 5, akc = tid & 31;  // A staging: row, k-quad

    float4v acc = {0.f, 0.f, 0.f, 0.f};

    // ---------------- Phase 1: GEMM1 (16 x 4096 @ 4096 x 128, bf16 MFMA) ----
    // BK=128 per step; ping-pong register prefetch one tile ahead.
    const float* xp = X + (size_t)(r0 + ar) * K_DIM + akc * 4;
    const unsigned short* wp = Wt + (size_t)(tid >> 4) * K_DIM + (tid & 15) * 8;
    unsigned short* aw = &Asm_[ar * 136 + akc * 4];
    unsigned short* bw = &Bsm_[(tid >> 4) * 136 + (tid & 15) * 8];

    float4 xa, xb;
    uint4 ba0, ba1, ba2, ba3, bb0, bb1, bb2, bb3;

    LOADT(0, xa, ba0, ba1, ba2, ba3);
#pragma unroll 1
    for (int kk = 0; kk < K_DIM; kk += 256) {
        STORET(xa, ba0, ba1, ba2, ba3);
        __syncthreads();
        LOADT(kk + 128, xb, bb0, bb1, bb2, bb3);  // covered by MFMA + barrier
        MF();
        __syncthreads();
        STORET(xb, bb0, bb1, bb2, bb3);
        __syncthreads();
        if (kk + 256 < K_DIM) LOADT(kk + 256, xa, ba0, ba1, ba2, ba3);
        MF();
        __syncthreads();
    }

    // Epilogue: C/D layout col=lane&15, row=quad*4+reg. Write h1 into hs.
    {
        const int c = w * 16 + m;
        const float bv = (c < 64) ? bC1[c] : bR1[c - 64];
#pragma unroll
        for (int i = 0; i < 4; ++i) {
            int r = q * 4 + i;
            float v = acc[i] + bv; v = v > 0.f ? v : 0.f;
            hs[r * 132 + c] = v;
        }
    }
    // Stage W2 = [WC2 | WR2] into LDS (64 x 128 f32), 2048 float4 / 512 thr.
#pragma unroll
    for (int p = 0; p < 4; ++p) {
        int fi = p * 512 + tid;
        int k = fi >> 5, c4 = fi & 31;
        int c = c4 * 4;
        const float* wsrc = (c < 64) ? (WC2 + (size_t)k * 64 + c)
                                     : (WR2 + (size_t)k * 64 + (c - 64));
        *(float4*)&W2s[k * 128 + c] = *(const float4*)wsrc;
    }
    __syncthreads();

    // ---------------- Phase 2: layer 2 (h2 = relu(h1 @ W2 + b2)) -----------
    const int rg = tid >> 5;          // 16 rows, 1 per row-group
    const int cg = tid & 31;          // 32 col quads
    const int koff2 = (cg < 16) ? 0 : 64;
    float acc2[4];
    {
        int c = cg * 4;
        const float* bsrc = (c < 64) ? (bC2 + c) : (bR2 + (c - 64));
#pragma unroll
        for (int j = 0; j < 4; ++j) acc2[j] = bsrc[j];
    }
    for (int k = 0; k < 64; ++k) {
        float4 wv = *(const float4*)&W2s[k * 128 + cg * 4];
        float a = hs[rg * 132 + koff2 + k];
        acc2[0] += a * wv.x; acc2[1] += a * wv.y;
        acc2[2] += a * wv.z; acc2[3] += a * wv.w;
    }
    float4 h2v;
    h2v.x = acc2[0] > 0.f ? acc2[0] : 0.f;
    h2v.y = acc2[1] > 0.f ? acc2[1] : 0.f;
    h2v.z = acc2[2] > 0.f ? acc2[2] : 0.f;
    h2v.w = acc2[3] > 0.f ? acc2[3] : 0.f;
    __syncthreads();                   // all reads of hs(h1)/W2s done
    *(float4*)&hs[rg * 132 + cg * 4] = h2v;   // hs now holds h2
    __syncthreads();

    // ---------------- Phase 3: layer 3 -> fl[16][288] (overlays W2s) -------
#pragma unroll 1
    for (int pass = 0; pass < 3; ++pass) {
        int c = pass * 128 + cg * 4;
        if (c < 288) {
            const int brn = (c >= 144);
            const int cl = c - (brn ? 144 : 0);
            const float* W3 = brn ? WR3 : WC3;
            const float* b3 = brn ? bR3 : bC3;
            const int ko = brn ? 64 : 0;
            float a3[4];
#pragma unroll
            for (int j = 0; j < 4; ++j) a3[j] = b3[cl + j];
            for (int k = 0; k < 64; ++k) {
                float4 wv = *(const float4*)(W3 + (size_t)k * OUTD + cl);
                float a = hs[rg * 132 + ko + k];
                a3[0] += a * wv.x; a3[1] += a * wv.y;
                a3[2] += a * wv.z; a3[3] += a * wv.w;
            }
            float4 v; v.x = a3[0]; v.y = a3[1]; v.z = a3[2]; v.w = a3[3];
            *(float4*)&fl[rg * 288 + c] = v;
        }
    }
    __syncthreads();

    // ---------------- Phase 4: softplus on the 12 diag reals per (row,brn) -
    if (tid < 384) {
        int r = tid / 24, rem = tid % 24;
        int brn = rem / 12, ii = rem % 12;
        float* f = &fl[r * 288 + brn * 144];
        int d = ii * (ii + 1) / 2 + ii;
        float xv = f[d];
        f[d] = (xv > 20.f) ? xv : log1pf(expf(xv));
    }
    __syncthreads();

    // ---------------- Phase 5: C = L L^H, Hermitian mirror, write OUT ------
    // IM-FIRST interleaved: one u32 = (re<<16)|im per complex element.
    unsigned int* O32 = (unsigned int*)OUT;
    for (int task = tid; task < 16 * 2 * 78; task += 512) {
        int r = task / 156, rem = task % 156;
        int brn = rem / 78, p = rem % 78;
        int i = 0;
        while (p >= (i + 1) * (i + 2) / 2) ++i;
        int j = p - i * (i + 1) / 2;              // j <= i
        const float* f = &fl[r * 288 + brn * 144]; // reals (diag softplus'd)
        const float* g = f + 78;                   // strict-lower imags
        const int ti = i * (i + 1) / 2, tj = j * (j + 1) / 2;
        const int si = i * (i - 1) / 2, sj = j * (j - 1) / 2;
        float re = 0.f, im = 0.f;
        for (int k = 0; k <= j; ++k) {
            float ar_ = f[ti + k];
            float ai  = (k == i) ? 0.f : g[si + k];
            float br_ = f[tj + k];
            float bi  = (k == j) ? 0.f : g[sj + k];
            re += ar_ * br_ + ai * bi;             // Re(L[i] . conj(L[j]))
            im += ai * br_ - ar_ * bi;             // Im
        }
        unsigned int reb = (unsigned int)f2bf(re);
        unsigned int imb = (unsigned int)f2bf(im);
        unsigned int imn = (unsigned int)f2bf(-im);
        size_t base = brn ? (size_t)PLANE : 0;     // in u32 units
        size_t q1 = (size_t)(r0 + r) * 144 + (size_t)(i * 12 + j);
        O32[base + q1] = imb | (reb << 16);        // imag low, real high
        if (i != j) {
            size_t q2 = (size_t)(r0 + r) * 144 + (size_t)(j * 12 + i);
            O32[base + q2] = imn | (reb << 16);
        }
    }
}

// ---------------------------------------------------------------------------
extern "C" void kernel_launch(void* const* d_in, const int* in_sizes, int n_in,
                              void* d_out, int out_size, void* d_ws, size_t ws_size,
                              hipStream_t stream) {
    const float* X   = (const float*)d_in[0];
    const float* WC1 = (const float*)d_in[1];
    const float* bC1 = (const float*)d_in[2];
    const float* WC2 = (const float*)d_in[3];
    const float* bC2 = (const float*)d_in[4];
    const float* WC3 = (const float*)d_in[5];
    const float* bC3 = (const float*)d_in[6];
    const float* WR1 = (const float*)d_in[7];
    const float* bR1 = (const float*)d_in[8];
    const float* WR2 = (const float*)d_in[9];
    const float* bR2 = (const float*)d_in[10];
    const float* WR3 = (const float*)d_in[11];
    const float* bR3 = (const float*)d_in[12];

    unsigned short* Wt = (unsigned short*)d_ws;   // 128 x 4096 bf16 = 1 MB
    unsigned short* OUT = (unsigned short*)d_out; // bf16, im-first interleaved

    wt_kernel<<<dim3(64, 2), 256, 0, stream>>>(WC1, WR1, Wt);
    fused_kernel<<<M_ROWS / 16, 512, 0, stream>>>(
        X, Wt, bC1, bR1, WC2, bC2, WR2, bR2, WC3, bC3, WR3, bR3, OUT);
}